// Round 16
// baseline (197.560 us; speedup 1.0000x reference)
//
#include <hip/hip_runtime.h>
#include <hip/hip_bf16.h>
#include <math.h>

// Problem constants
#define TT    2048
#define HH    8
#define RDIM  32
#define BB    2

typedef float  f4  __attribute__((ext_vector_type(4)));
typedef int    i4  __attribute__((ext_vector_type(4)));
typedef uint   u2  __attribute__((ext_vector_type(2)));
typedef uint   u4  __attribute__((ext_vector_type(4)));
typedef short  s8v __attribute__((ext_vector_type(8)));   // 8 x bf16 bits (4 VGPR)

// round-to-nearest f32 -> bf16 bits
__device__ __forceinline__ uint rnd16(float x) {
    return (__float_as_uint(x) + 0x8000u) >> 16;
}

union v8cast { u4 u; s8v s; };

// ---------------------------------------------------------------------------
// Kernel 0: Wt prep — transpose (Wq|Wk)[1024][256+256] f32 -> Wt[512][1024]
// bf16 (Wt[n][k] = W[k][n]). LDS-tiled 64x64. 1 MB output, L2-resident.
// ---------------------------------------------------------------------------
__global__ __launch_bounds__(256) void wt_prep(
    const float* __restrict__ Wq,
    const float* __restrict__ Wk,
    ushort* __restrict__ Wt)
{
    __shared__ float T[64][68];
    const int k0 = blockIdx.x * 64;
    const int n0 = blockIdx.y * 64;
    const float* W = (n0 < 256) ? Wq : Wk;
    const int nloc = n0 & 255;
    const int tid = threadIdx.x;

    #pragma unroll
    for (int r = 0; r < 4; ++r) {
        int kl  = (tid >> 4) + r * 16;
        int nl4 = (tid & 15) * 4;
        f4 v = *(const f4*)&W[(size_t)(k0 + kl) * 256 + nloc + nl4];
        T[nl4 + 0][kl] = v.x;
        T[nl4 + 1][kl] = v.y;
        T[nl4 + 2][kl] = v.z;
        T[nl4 + 3][kl] = v.w;
    }
    __syncthreads();

    const int nl = tid >> 2;
    const int kq = (tid & 3) * 16;
    u4 o0, o1;
    #pragma unroll
    for (int j = 0; j < 4; ++j) {
        uint lo = rnd16(T[nl][kq + 2 * j]);
        uint hi = rnd16(T[nl][kq + 2 * j + 1]);
        ((uint*)&o0)[j] = (hi << 16) | lo;
    }
    #pragma unroll
    for (int j = 0; j < 4; ++j) {
        uint lo = rnd16(T[nl][kq + 8 + 2 * j]);
        uint hi = rnd16(T[nl][kq + 8 + 2 * j + 1]);
        ((uint*)&o1)[j] = (hi << 16) | lo;
    }
    ushort* dst = Wt + (size_t)(n0 + nl) * 1024 + k0 + kq;
    *(u4*)dst = o0;
    *(u4*)(dst + 8) = o1;
}

// ---------------------------------------------------------------------------
// Kernel 1: MFMA projection.  sq/sk[m][n] = sum_k x[m][k] * Wt[n][k]
// mfma(A=Wt_tile, B=x_tile): D lane owns col m = lane&15, 4 consecutive n.
// ---------------------------------------------------------------------------
__global__ __launch_bounds__(256) void proj_mfma(
    const float* __restrict__ x,       // [4096][1024] f32
    const ushort* __restrict__ Wt,     // [512][1024] bf16 bits
    ushort* __restrict__ sqb,          // [4096][256] bf16 bits
    ushort* __restrict__ skb)          // [4096][256] bf16 bits
{
    const int tid = threadIdx.x;
    const int l   = tid & 63;
    const int w   = __builtin_amdgcn_readfirstlane(tid) >> 6;  // 0..3
    const int cl  = l & 15;
    const int g4  = l >> 4;
    const int m0  = (blockIdx.x * 4 + w) * 16;   // m-tile
    const int n0  = blockIdx.y * 64;             // n-block (64 wide)

    f4 acc0 = {0,0,0,0}, acc1 = {0,0,0,0}, acc2 = {0,0,0,0}, acc3 = {0,0,0,0};

    const float*  xrow = x + (size_t)(m0 + cl) * 1024;
    const ushort* wbase = Wt + (size_t)(n0 + cl) * 1024;

    for (int ks = 0; ks < 32; ++ks) {
        const int k = ks * 32 + g4 * 8;
        f4 xa = *(const f4*)&xrow[k];
        f4 xb2 = *(const f4*)&xrow[k + 4];
        v8cast bf;
        ((uint*)&bf.u)[0] = (rnd16(xa.y) << 16) | rnd16(xa.x);
        ((uint*)&bf.u)[1] = (rnd16(xa.w) << 16) | rnd16(xa.z);
        ((uint*)&bf.u)[2] = (rnd16(xb2.y) << 16) | rnd16(xb2.x);
        ((uint*)&bf.u)[3] = (rnd16(xb2.w) << 16) | rnd16(xb2.z);
        s8v a0 = *(const s8v*)(wbase + 0 * 16 * 1024 + k);
        s8v a1 = *(const s8v*)(wbase + 1 * 16 * 1024 + k);
        s8v a2 = *(const s8v*)(wbase + 2 * 16 * 1024 + k);
        s8v a3 = *(const s8v*)(wbase + 3 * 16 * 1024 + k);
        acc0 = __builtin_amdgcn_mfma_f32_16x16x32_bf16(a0, bf.s, acc0, 0, 0, 0);
        acc1 = __builtin_amdgcn_mfma_f32_16x16x32_bf16(a1, bf.s, acc1, 0, 0, 0);
        acc2 = __builtin_amdgcn_mfma_f32_16x16x32_bf16(a2, bf.s, acc2, 0, 0, 0);
        acc3 = __builtin_amdgcn_mfma_f32_16x16x32_bf16(a3, bf.s, acc3, 0, 0, 0);
    }

    const int m = m0 + cl;
    const int nbase = n0 + g4 * 4;
    ushort* obase = (n0 < 256) ? (sqb + (size_t)m * 256 + nbase)
                               : (skb + (size_t)m * 256 + (nbase - 256));
    f4 accs[4] = {acc0, acc1, acc2, acc3};
    #pragma unroll
    for (int t = 0; t < 4; ++t) {
        u2 pk;
        pk.x = (rnd16(accs[t][1]) << 16) | rnd16(accs[t][0]);
        pk.y = (rnd16(accs[t][3]) << 16) | rnd16(accs[t][2]);
        *(u2*)(obase + t * 16) = pk;
    }
}

// ---------------------------------------------------------------------------
// Kernel 2: MFMA scores + mask + gumbel + softmax (swapped operands).
// R14: 512-thr blocks (R10's no-spill shape) + launch_bounds(512,2) to lift
// the VGPR ceiling; exp values live in LDS (p_lds, 64KB) instead of 32 VGPRs;
// explicit ping-pong pipeline one tile-PAIR ahead (static parity indices) ->
// ~6 outstanding loads/wave without spilling. Gumbel loads NT (read-once);
// zero-fill stores NT (full-line); pass-2 stores plain cached.
// ---------------------------------------------------------------------------
__global__ __launch_bounds__(512, 2) void score_mfma(
    const ushort* __restrict__ sqb,     // [4096][256] bf16 bits
    const ushort* __restrict__ skb,     // [4096][256] bf16 bits
    const float*  __restrict__ gumbel,  // [B,H,T,T] f32
    const int*    __restrict__ mask,    // [H,T,T] int32 bool
    float* __restrict__ out)            // [B,H,T,T] f32
{
    const int tid = threadIdx.x;
    const int l   = tid & 63;
    const int w   = __builtin_amdgcn_readfirstlane(tid) >> 6;  // wave id 0..7
    const int bh  = blockIdx.x & 15;
    const int sp  = blockIdx.x >> 4;     // 0..63
    const int h   = bh & (HH - 1);
    const int b   = bh >> 3;
    const int cl  = l & 15;              // C col -> output row i offset
    const int g4  = l >> 4;              // 0..3  -> j sub-block
    const float RS = 0.17677669529663687f;  // 1/sqrt(RD)

    __shared__ u2    p_lds[8][16][64];   // exp packed 2xbf16 per uint: 64 KB
    __shared__ float sums_lds[8][16];

    const ushort* sqbase = sqb + ((size_t)b * TT) * 256 + h * RDIM + g4 * 8;
    const ushort* skbase = skb + ((size_t)b * TT) * 256 + h * RDIM + g4 * 8;
    const float*  gb = gumbel + (size_t)bh * TT * TT;
    const int*    mb = mask + (size_t)h * TT * TT;
    float*        ob = out + (size_t)bh * TT * TT;

    #pragma unroll 1
    for (int half = 0; half < 2; ++half) {
        const int s      = half ? (127 - sp) : sp;
        const int i0     = s * 16;
        const int ntiles = s + 1;        // live 16-col tiles (max 128)
        const int zstart = ntiles * 16;
        const int i      = i0 + cl;      // this lane's output row

        // B fragment (sq row i): strip-invariant
        s8v bfrag = *(const s8v*)(sqbase + (size_t)i * 256);

        const float* grow = gb + (size_t)i * TT;
        const int*   mrow = mb + (size_t)i * TT;
        float*       orow = ob + (size_t)i * TT;

        // ping-pong pipeline state: one tile-pair ahead (static indices)
        s8v af[2][2];
        f4  gv[2][2];
        i4  mv[2][2];

        #define PLOAD(buf_, it_) do {                                          \
            _Pragma("unroll")                                                  \
            for (int u_ = 0; u_ < 2; ++u_) {                                   \
                const int jt_ = 2 * w + (it_) * 16 + u_;                       \
                if (jt_ < ntiles) {                                            \
                    af[buf_][u_] = *(const s8v*)(skbase +                      \
                                     (size_t)(jt_ * 16 + cl) * 256);           \
                    const int jb_ = jt_ * 16 + g4 * 4;                         \
                    gv[buf_][u_] = __builtin_nontemporal_load(                 \
                                     (const f4*)&grow[jb_]);                   \
                    mv[buf_][u_] = *(const i4*)&mrow[jb_];                     \
                }                                                              \
            }                                                                  \
        } while (0)

        PLOAD(0, 0);

        float sum = 0.f;
        #pragma unroll
        for (int it = 0; it < 8; ++it) {
            const int pb = it & 1;                 // literal per iteration
            if (it < 7) PLOAD(pb ^ 1, it + 1);     // prefetch next pair
            #pragma unroll
            for (int u = 0; u < 2; ++u) {
                const int jt = 2 * w + it * 16 + u;
                if (jt < ntiles) {
                    f4 z = {0.f, 0.f, 0.f, 0.f};
                    f4 c = __builtin_amdgcn_mfma_f32_16x16x32_bf16(
                               af[pb][u], bfrag, z, 0, 0, 0);
                    const int jb = jt * 16 + g4 * 4;   // 4 consecutive cols
                    f4 gvv = gv[pb][u];
                    i4 mvv = mv[pb][u];
                    float e0 = (jb + 0 > i || mvv.x) ? 0.f : __expf(fmaf(c[0], RS, gvv.x));
                    float e1 = (jb + 1 > i || mvv.y) ? 0.f : __expf(fmaf(c[1], RS, gvv.y));
                    float e2 = (jb + 2 > i || mvv.z) ? 0.f : __expf(fmaf(c[2], RS, gvv.z));
                    float e3 = (jb + 3 > i || mvv.w) ? 0.f : __expf(fmaf(c[3], RS, gvv.w));
                    sum += (e0 + e1) + (e2 + e3);
                    u2 pk;
                    pk.x = (rnd16(e1) << 16) | rnd16(e0);
                    pk.y = (rnd16(e3) << 16) | rnd16(e2);
                    p_lds[w][it * 2 + u][l] = pk;
                }
            }
        }
        #undef PLOAD

        // ---- row-sum reduce: across g4 groups, then across 8 waves ----
        sum += __shfl_xor(sum, 16);
        sum += __shfl_xor(sum, 32);
        if (l < 16) sums_lds[w][l] = sum;
        __syncthreads();
        float t = 0.f;
        #pragma unroll
        for (int ww = 0; ww < 8; ++ww) t += sums_lds[ww][cl];
        const float rinv = 1.0f / t;     // diagonal always live -> t > 0
        __syncthreads();                 // LDS reused by next half

        // ---- pass 2: read p from LDS, unpack + scale + store ----
        #pragma unroll
        for (int sx = 0; sx < 16; ++sx) {
            const int jt = 2 * w + (sx >> 1) * 16 + (sx & 1);
            if (jt < ntiles) {
                const int jb = jt * 16 + g4 * 4;
                u2 pk = p_lds[w][sx][l];
                f4 v;
                v.x = __uint_as_float(pk.x << 16) * rinv;
                v.y = __uint_as_float(pk.x & 0xffff0000u) * rinv;
                v.z = __uint_as_float(pk.y << 16) * rinv;
                v.w = __uint_as_float(pk.y & 0xffff0000u) * rinv;
                *(f4*)&orow[jb] = v;
            }
        }

        // ---- zero-fill cols beyond the causal frontier (full lines, NT) ----
        for (int r = 0; r < 16; ++r) {
            for (int cz = zstart + tid * 4; cz < TT; cz += 512 * 4) {
                f4 zz = {0.f, 0.f, 0.f, 0.f};
                __builtin_nontemporal_store(zz, (f4*)&ob[(size_t)(i0 + r) * TT + cz]);
            }
        }
    }
}

extern "C" void kernel_launch(void* const* d_in, const int* in_sizes, int n_in,
                              void* d_out, int out_size, void* d_ws, size_t ws_size,
                              hipStream_t stream) {
    const float* x      = (const float*)d_in[0];
    const int*   bmask  = (const int*)d_in[1];   // bool -> int32 per harness
    const float* gumbel = (const float*)d_in[2];
    const float* Wq     = (const float*)d_in[3];
    const float* Wk     = (const float*)d_in[4];
    float* out = (float*)d_out;

    ushort* sqb = (ushort*)d_ws;                       // 4096*256 bf16 = 2 MB
    ushort* skb = sqb + (size_t)4096 * 256;            // 2 MB
    ushort* Wt  = skb + (size_t)4096 * 256;            // 512*1024 bf16 = 1 MB

    wt_prep<<<dim3(16, 8), 256, 0, stream>>>(Wq, Wk, Wt);
    proj_mfma<<<dim3(64, 8), 256, 0, stream>>>(x, Wt, sqb, skb);

    // 16 bh x 64 balanced strip-pairs, 512 thr (8 waves) each
    score_mfma<<<1024, 512, 0, stream>>>(sqb, skb, gumbel, bmask, out);
}

// Round 17
// 196.469 us; speedup vs baseline: 1.0056x; 1.0056x over previous
//
#include <hip/hip_runtime.h>
#include <hip/hip_bf16.h>
#include <math.h>

// Problem constants
#define TT    2048
#define HH    8
#define RDIM  32
#define BB    2

typedef float  f4  __attribute__((ext_vector_type(4)));
typedef int    i4  __attribute__((ext_vector_type(4)));
typedef uint   u2  __attribute__((ext_vector_type(2)));
typedef uint   u4  __attribute__((ext_vector_type(4)));
typedef short  s8v __attribute__((ext_vector_type(8)));   // 8 x bf16 bits (4 VGPR)

// round-to-nearest f32 -> bf16 bits
__device__ __forceinline__ uint rnd16(float x) {
    return (__float_as_uint(x) + 0x8000u) >> 16;
}

union v8cast { u4 u; s8v s; };

// ---------------------------------------------------------------------------
// Kernel 0: Wt prep — transpose (Wq|Wk)[1024][256+256] f32 -> Wt[512][1024]
// bf16 (Wt[n][k] = W[k][n]). LDS-tiled 64x64. 1 MB output, L2-resident.
// ---------------------------------------------------------------------------
__global__ __launch_bounds__(256) void wt_prep(
    const float* __restrict__ Wq,
    const float* __restrict__ Wk,
    ushort* __restrict__ Wt)
{
    __shared__ float T[64][68];
    const int k0 = blockIdx.x * 64;
    const int n0 = blockIdx.y * 64;
    const float* W = (n0 < 256) ? Wq : Wk;
    const int nloc = n0 & 255;
    const int tid = threadIdx.x;

    #pragma unroll
    for (int r = 0; r < 4; ++r) {
        int kl  = (tid >> 4) + r * 16;
        int nl4 = (tid & 15) * 4;
        f4 v = *(const f4*)&W[(size_t)(k0 + kl) * 256 + nloc + nl4];
        T[nl4 + 0][kl] = v.x;
        T[nl4 + 1][kl] = v.y;
        T[nl4 + 2][kl] = v.z;
        T[nl4 + 3][kl] = v.w;
    }
    __syncthreads();

    const int nl = tid >> 2;
    const int kq = (tid & 3) * 16;
    u4 o0, o1;
    #pragma unroll
    for (int j = 0; j < 4; ++j) {
        uint lo = rnd16(T[nl][kq + 2 * j]);
        uint hi = rnd16(T[nl][kq + 2 * j + 1]);
        ((uint*)&o0)[j] = (hi << 16) | lo;
    }
    #pragma unroll
    for (int j = 0; j < 4; ++j) {
        uint lo = rnd16(T[nl][kq + 8 + 2 * j]);
        uint hi = rnd16(T[nl][kq + 8 + 2 * j + 1]);
        ((uint*)&o1)[j] = (hi << 16) | lo;
    }
    ushort* dst = Wt + (size_t)(n0 + nl) * 1024 + k0 + kq;
    *(u4*)dst = o0;
    *(u4*)(dst + 8) = o1;
}

// ---------------------------------------------------------------------------
// Kernel 1: MFMA projection.  sq/sk[m][n] = sum_k x[m][k] * Wt[n][k]
// mfma(A=Wt_tile, B=x_tile): D lane owns col m = lane&15, 4 consecutive n.
// ---------------------------------------------------------------------------
__global__ __launch_bounds__(256) void proj_mfma(
    const float* __restrict__ x,       // [4096][1024] f32
    const ushort* __restrict__ Wt,     // [512][1024] bf16 bits
    ushort* __restrict__ sqb,          // [4096][256] bf16 bits
    ushort* __restrict__ skb)          // [4096][256] bf16 bits
{
    const int tid = threadIdx.x;
    const int l   = tid & 63;
    const int w   = __builtin_amdgcn_readfirstlane(tid) >> 6;  // 0..3
    const int cl  = l & 15;
    const int g4  = l >> 4;
    const int m0  = (blockIdx.x * 4 + w) * 16;   // m-tile
    const int n0  = blockIdx.y * 64;             // n-block (64 wide)

    f4 acc0 = {0,0,0,0}, acc1 = {0,0,0,0}, acc2 = {0,0,0,0}, acc3 = {0,0,0,0};

    const float*  xrow = x + (size_t)(m0 + cl) * 1024;
    const ushort* wbase = Wt + (size_t)(n0 + cl) * 1024;

    for (int ks = 0; ks < 32; ++ks) {
        const int k = ks * 32 + g4 * 8;
        f4 xa = *(const f4*)&xrow[k];
        f4 xb2 = *(const f4*)&xrow[k + 4];
        v8cast bf;
        ((uint*)&bf.u)[0] = (rnd16(xa.y) << 16) | rnd16(xa.x);
        ((uint*)&bf.u)[1] = (rnd16(xa.w) << 16) | rnd16(xa.z);
        ((uint*)&bf.u)[2] = (rnd16(xb2.y) << 16) | rnd16(xb2.x);
        ((uint*)&bf.u)[3] = (rnd16(xb2.w) << 16) | rnd16(xb2.z);
        s8v a0 = *(const s8v*)(wbase + 0 * 16 * 1024 + k);
        s8v a1 = *(const s8v*)(wbase + 1 * 16 * 1024 + k);
        s8v a2 = *(const s8v*)(wbase + 2 * 16 * 1024 + k);
        s8v a3 = *(const s8v*)(wbase + 3 * 16 * 1024 + k);
        acc0 = __builtin_amdgcn_mfma_f32_16x16x32_bf16(a0, bf.s, acc0, 0, 0, 0);
        acc1 = __builtin_amdgcn_mfma_f32_16x16x32_bf16(a1, bf.s, acc1, 0, 0, 0);
        acc2 = __builtin_amdgcn_mfma_f32_16x16x32_bf16(a2, bf.s, acc2, 0, 0, 0);
        acc3 = __builtin_amdgcn_mfma_f32_16x16x32_bf16(a3, bf.s, acc3, 0, 0, 0);
    }

    const int m = m0 + cl;
    const int nbase = n0 + g4 * 4;
    ushort* obase = (n0 < 256) ? (sqb + (size_t)m * 256 + nbase)
                               : (skb + (size_t)m * 256 + (nbase - 256));
    f4 accs[4] = {acc0, acc1, acc2, acc3};
    #pragma unroll
    for (int t = 0; t < 4; ++t) {
        u2 pk;
        pk.x = (rnd16(accs[t][1]) << 16) | rnd16(accs[t][0]);
        pk.y = (rnd16(accs[t][3]) << 16) | rnd16(accs[t][2]);
        *(u2*)(obase + t * 16) = pk;
    }
}

// ---------------------------------------------------------------------------
// Kernel 2: MFMA scores + mask + gumbel + softmax.
// R17: global pair counter gp=0..15 spans both halves (gp<8 -> strip sp,
// gp>=8 -> strip 127-sp); 3 rotating reg buffers (buf=gp%3), depth-2
// lookahead -> 12-18 loads in flight/wave. Half-1's first two pairs are
// prefetched AFTER the half-0 reduce barrier (so the barrier's implicit
// vmcnt(0) drain can't stall on them) and overlap pass2+zerofill.
// exp values in LDS (p_lds), sums double-buffered (no second barrier).
// Plain cached gumbel loads (R16: NT loads broke pair line-reuse, +25MB).
// ---------------------------------------------------------------------------
__global__ __launch_bounds__(512, 2) void score_mfma(
    const ushort* __restrict__ sqb,     // [4096][256] bf16 bits
    const ushort* __restrict__ skb,     // [4096][256] bf16 bits
    const float*  __restrict__ gumbel,  // [B,H,T,T] f32
    const int*    __restrict__ mask,    // [H,T,T] int32 bool
    float* __restrict__ out)            // [B,H,T,T] f32
{
    const int tid = threadIdx.x;
    const int l   = tid & 63;
    const int w   = __builtin_amdgcn_readfirstlane(tid) >> 6;  // wave id 0..7
    const int bh  = blockIdx.x & 15;
    const int sp  = blockIdx.x >> 4;     // 0..63
    const int h   = bh & (HH - 1);
    const int b   = bh >> 3;
    const int cl  = l & 15;              // C col -> output row i offset
    const int g4  = l >> 4;              // 0..3  -> j sub-block
    const float RS = 0.17677669529663687f;  // 1/sqrt(RD)

    __shared__ u2    p_lds[8][16][64];   // exp packed 2xbf16 per uint: 64 KB
    __shared__ float sums_lds[2][8][16]; // double-buffered per half

    const ushort* sqbase = sqb + ((size_t)b * TT) * 256 + h * RDIM + g4 * 8;
    const ushort* skbase = skb + ((size_t)b * TT) * 256 + h * RDIM + g4 * 8;
    const float*  gb = gumbel + (size_t)bh * TT * TT;
    const int*    mb = mask + (size_t)h * TT * TT;
    float*        ob = out + (size_t)bh * TT * TT;

    // per-half geometry (all wave-uniform except i/row pointers)
    const int s0_ = sp,        s1_ = 127 - sp;
    const int i00 = s0_ * 16,  i01 = s1_ * 16;
    const int nt0 = s0_ + 1,   nt1 = s1_ + 1;
    const int i_0 = i00 + cl,  i_1 = i01 + cl;  // lane's output rows
    const float* grow0 = gb + (size_t)i_0 * TT;
    const float* grow1 = gb + (size_t)i_1 * TT;
    const int*   mrow0 = mb + (size_t)i_0 * TT;
    const int*   mrow1 = mb + (size_t)i_1 * TT;
    float*       orow0 = ob + (size_t)i_0 * TT;
    float*       orow1 = ob + (size_t)i_1 * TT;

    // sq fragments for both halves (independent loads, issued up front)
    s8v bf0 = *(const s8v*)(sqbase + (size_t)i_0 * 256);
    s8v bf1 = *(const s8v*)(sqbase + (size_t)i_1 * 256);

    // rotating pipeline buffers (all indices compile-time after unroll)
    s8v af[3][2];
    f4  gv[3][2];
    i4  mv[3][2];

    #define PLOAD(gp_) do {                                                   \
        const int buf_ = (gp_) % 3;                                           \
        const int pr_  = (gp_) & 7;                                           \
        const bool hh_ = (gp_) >= 8;                                          \
        const int nt_  = hh_ ? nt1 : nt0;                                     \
        const float* g_ = hh_ ? grow1 : grow0;                                \
        const int*   m_ = hh_ ? mrow1 : mrow0;                                \
        _Pragma("unroll")                                                     \
        for (int u_ = 0; u_ < 2; ++u_) {                                      \
            const int jt_ = 2 * w + pr_ * 16 + u_;                            \
            if (jt_ < nt_) {                                                  \
                af[buf_][u_] = *(const s8v*)(skbase +                         \
                                 (size_t)(jt_ * 16 + cl) * 256);              \
                const int jb_ = jt_ * 16 + g4 * 4;                            \
                gv[buf_][u_] = *(const f4*)&g_[jb_];                          \
                mv[buf_][u_] = *(const i4*)&m_[jb_];                          \
            }                                                                 \
        }                                                                     \
    } while (0)

    #define PCOMPUTE(gp_, sum_) do {                                          \
        const int buf_ = (gp_) % 3;                                           \
        const int pr_  = (gp_) & 7;                                           \
        const bool hh_ = (gp_) >= 8;                                          \
        const int nt_  = hh_ ? nt1 : nt0;                                     \
        const int iw_  = hh_ ? i_1 : i_0;                                     \
        const s8v bfr_ = hh_ ? bf1 : bf0;                                     \
        _Pragma("unroll")                                                     \
        for (int u_ = 0; u_ < 2; ++u_) {                                      \
            const int jt_ = 2 * w + pr_ * 16 + u_;                            \
            if (jt_ < nt_) {                                                  \
                f4 z_ = {0.f, 0.f, 0.f, 0.f};                                 \
                f4 c_ = __builtin_amdgcn_mfma_f32_16x16x32_bf16(              \
                            af[buf_][u_], bfr_, z_, 0, 0, 0);                 \
                const int jb_ = jt_ * 16 + g4 * 4;                            \
                f4 gvv_ = gv[buf_][u_];                                       \
                i4 mvv_ = mv[buf_][u_];                                       \
                float e0_ = (jb_ + 0 > iw_ || mvv_.x) ? 0.f : __expf(fmaf(c_[0], RS, gvv_.x)); \
                float e1_ = (jb_ + 1 > iw_ || mvv_.y) ? 0.f : __expf(fmaf(c_[1], RS, gvv_.y)); \
                float e2_ = (jb_ + 2 > iw_ || mvv_.z) ? 0.f : __expf(fmaf(c_[2], RS, gvv_.z)); \
                float e3_ = (jb_ + 3 > iw_ || mvv_.w) ? 0.f : __expf(fmaf(c_[3], RS, gvv_.w)); \
                sum_ += (e0_ + e1_) + (e2_ + e3_);                            \
                u2 pk_;                                                       \
                pk_.x = (rnd16(e1_) << 16) | rnd16(e0_);                      \
                pk_.y = (rnd16(e3_) << 16) | rnd16(e2_);                      \
                p_lds[w][pr_ * 2 + u_][l] = pk_;                              \
            }                                                                 \
        }                                                                     \
    } while (0)

    #define REDUCE(hbuf_, sum_, rinv_) do {                                   \
        float v_ = sum_;                                                      \
        v_ += __shfl_xor(v_, 16);                                             \
        v_ += __shfl_xor(v_, 32);                                             \
        if (l < 16) sums_lds[hbuf_][w][l] = v_;                               \
        __syncthreads();                                                      \
        float t_ = 0.f;                                                       \
        _Pragma("unroll")                                                     \
        for (int ww_ = 0; ww_ < 8; ++ww_) t_ += sums_lds[hbuf_][ww_][cl];     \
        rinv_ = 1.0f / t_;                                                    \
    } while (0)

    #define PASS2(rinv_, nt_, orow_) do {                                     \
        _Pragma("unroll")                                                     \
        for (int sx_ = 0; sx_ < 16; ++sx_) {                                  \
            const int jt_ = 2 * w + (sx_ >> 1) * 16 + (sx_ & 1);              \
            if (jt_ < nt_) {                                                  \
                const int jb_ = jt_ * 16 + g4 * 4;                            \
                u2 pk_ = p_lds[w][sx_][l];                                    \
                f4 v_;                                                        \
                v_.x = __uint_as_float(pk_.x << 16) * rinv_;                  \
                v_.y = __uint_as_float(pk_.x & 0xffff0000u) * rinv_;          \
                v_.z = __uint_as_float(pk_.y << 16) * rinv_;                  \
                v_.w = __uint_as_float(pk_.y & 0xffff0000u) * rinv_;          \
                *(f4*)&orow_[jb_] = v_;                                       \
            }                                                                 \
        }                                                                     \
    } while (0)

    #define ZFILL(i0_, nt_) do {                                              \
        const int zs_ = (nt_) * 16;                                           \
        for (int r_ = 0; r_ < 16; ++r_) {                                     \
            for (int cz_ = zs_ + tid * 4; cz_ < TT; cz_ += 512 * 4) {         \
                f4 zz_ = {0.f, 0.f, 0.f, 0.f};                                \
                __builtin_nontemporal_store(zz_,                              \
                    (f4*)&ob[(size_t)((i0_) + r_) * TT + cz_]);               \
            }                                                                 \
        }                                                                     \
    } while (0)

    // ---- prologue: pairs 0,1 of half 0 ----
    PLOAD(0);
    PLOAD(1);

    // ---- half 0 compute (gp = 0..7), depth-2 lookahead ----
    float sum0 = 0.f;
    #pragma unroll
    for (int gp = 0; gp < 8; ++gp) {
        if (gp + 2 < 8) PLOAD(gp + 2);
        PCOMPUTE(gp, sum0);
    }

    float rinv0;
    REDUCE(0, sum0, rinv0);

    // half-1 prefetch AFTER the barrier: overlaps pass2 + zero-fill
    PLOAD(8);
    PLOAD(9);

    PASS2(rinv0, nt0, orow0);
    ZFILL(i00, nt0);

    // ---- half 1 compute (gp = 8..15) ----
    float sum1 = 0.f;
    #pragma unroll
    for (int gp = 8; gp < 16; ++gp) {
        if (gp + 2 < 16) PLOAD(gp + 2);
        PCOMPUTE(gp, sum1);
    }

    float rinv1;
    REDUCE(1, sum1, rinv1);

    PASS2(rinv1, nt1, orow1);
    ZFILL(i01, nt1);

    #undef PLOAD
    #undef PCOMPUTE
    #undef REDUCE
    #undef PASS2
    #undef ZFILL
}

extern "C" void kernel_launch(void* const* d_in, const int* in_sizes, int n_in,
                              void* d_out, int out_size, void* d_ws, size_t ws_size,
                              hipStream_t stream) {
    const float* x      = (const float*)d_in[0];
    const int*   bmask  = (const int*)d_in[1];   // bool -> int32 per harness
    const float* gumbel = (const float*)d_in[2];
    const float* Wq     = (const float*)d_in[3];
    const float* Wk     = (const float*)d_in[4];
    float* out = (float*)d_out;

    ushort* sqb = (ushort*)d_ws;                       // 4096*256 bf16 = 2 MB
    ushort* skb = sqb + (size_t)4096 * 256;            // 2 MB
    ushort* Wt  = skb + (size_t)4096 * 256;            // 512*1024 bf16 = 1 MB

    wt_prep<<<dim3(16, 8), 256, 0, stream>>>(Wq, Wk, Wt);
    proj_mfma<<<dim3(64, 8), 256, 0, stream>>>(x, Wt, sqb, skb);

    // 16 bh x 64 balanced strip-pairs, 512 thr (8 waves) each
    score_mfma<<<1024, 512, 0, stream>>>(sqb, skb, gumbel, bmask, out);
}

// Round 18
// 190.485 us; speedup vs baseline: 1.0371x; 1.0314x over previous
//
#include <hip/hip_runtime.h>
#include <hip/hip_bf16.h>
#include <math.h>

// Problem constants
#define TT    2048
#define HH    8
#define RDIM  32
#define BB    2

typedef float  f4  __attribute__((ext_vector_type(4)));
typedef int    i4  __attribute__((ext_vector_type(4)));
typedef uint   u2  __attribute__((ext_vector_type(2)));
typedef uint   u4  __attribute__((ext_vector_type(4)));
typedef short  s8v __attribute__((ext_vector_type(8)));   // 8 x bf16 bits (4 VGPR)

// round-to-nearest f32 -> bf16 bits
__device__ __forceinline__ uint rnd16(float x) {
    return (__float_as_uint(x) + 0x8000u) >> 16;
}

union v8cast { u4 u; s8v s; };

// ---------------------------------------------------------------------------
// Kernel Z: zero-fill the causally-dead region (cols >= 16*(s+1) of each
// 16-row strip). Pure memset-class: full-line NT stores, no deps, launched
// first. Removes 134MB (36%) of score_mfma's traffic. Balanced strip-pair
// mapping (s, 127-s) -> uniform 32512 elements/block.
// ---------------------------------------------------------------------------
__global__ __launch_bounds__(512) void zfill(float* __restrict__ out)
{
    const int bh = blockIdx.x & 15;
    const int sp = blockIdx.x >> 4;      // 0..63
    const int tid = threadIdx.x;
    float* ob = out + (size_t)bh * TT * TT;

    #pragma unroll 1
    for (int half = 0; half < 2; ++half) {
        const int s  = half ? (127 - sp) : sp;
        const int i0 = s * 16;
        const int zs = (s + 1) * 16;     // first dead col (16-quantized)
        for (int r = 0; r < 16; ++r) {
            for (int cz = zs + tid * 4; cz < TT; cz += 512 * 4) {
                f4 zz = {0.f, 0.f, 0.f, 0.f};
                __builtin_nontemporal_store(zz, (f4*)&ob[(size_t)(i0 + r) * TT + cz]);
            }
        }
    }
}

// ---------------------------------------------------------------------------
// Kernel 0: Wt prep — transpose (Wq|Wk)[1024][256+256] f32 -> Wt[512][1024]
// bf16 (Wt[n][k] = W[k][n]). LDS-tiled 64x64. 1 MB output, L2-resident.
// ---------------------------------------------------------------------------
__global__ __launch_bounds__(256) void wt_prep(
    const float* __restrict__ Wq,
    const float* __restrict__ Wk,
    ushort* __restrict__ Wt)
{
    __shared__ float T[64][68];
    const int k0 = blockIdx.x * 64;
    const int n0 = blockIdx.y * 64;
    const float* W = (n0 < 256) ? Wq : Wk;
    const int nloc = n0 & 255;
    const int tid = threadIdx.x;

    #pragma unroll
    for (int r = 0; r < 4; ++r) {
        int kl  = (tid >> 4) + r * 16;
        int nl4 = (tid & 15) * 4;
        f4 v = *(const f4*)&W[(size_t)(k0 + kl) * 256 + nloc + nl4];
        T[nl4 + 0][kl] = v.x;
        T[nl4 + 1][kl] = v.y;
        T[nl4 + 2][kl] = v.z;
        T[nl4 + 3][kl] = v.w;
    }
    __syncthreads();

    const int nl = tid >> 2;
    const int kq = (tid & 3) * 16;
    u4 o0, o1;
    #pragma unroll
    for (int j = 0; j < 4; ++j) {
        uint lo = rnd16(T[nl][kq + 2 * j]);
        uint hi = rnd16(T[nl][kq + 2 * j + 1]);
        ((uint*)&o0)[j] = (hi << 16) | lo;
    }
    #pragma unroll
    for (int j = 0; j < 4; ++j) {
        uint lo = rnd16(T[nl][kq + 8 + 2 * j]);
        uint hi = rnd16(T[nl][kq + 8 + 2 * j + 1]);
        ((uint*)&o1)[j] = (hi << 16) | lo;
    }
    ushort* dst = Wt + (size_t)(n0 + nl) * 1024 + k0 + kq;
    *(u4*)dst = o0;
    *(u4*)(dst + 8) = o1;
}

// ---------------------------------------------------------------------------
// Kernel 1: MFMA projection.  sq/sk[m][n] = sum_k x[m][k] * Wt[n][k]
// mfma(A=Wt_tile, B=x_tile): D lane owns col m = lane&15, 4 consecutive n.
// ---------------------------------------------------------------------------
__global__ __launch_bounds__(256) void proj_mfma(
    const float* __restrict__ x,       // [4096][1024] f32
    const ushort* __restrict__ Wt,     // [512][1024] bf16 bits
    ushort* __restrict__ sqb,          // [4096][256] bf16 bits
    ushort* __restrict__ skb)          // [4096][256] bf16 bits
{
    const int tid = threadIdx.x;
    const int l   = tid & 63;
    const int w   = __builtin_amdgcn_readfirstlane(tid) >> 6;  // 0..3
    const int cl  = l & 15;
    const int g4  = l >> 4;
    const int m0  = (blockIdx.x * 4 + w) * 16;   // m-tile
    const int n0  = blockIdx.y * 64;             // n-block (64 wide)

    f4 acc0 = {0,0,0,0}, acc1 = {0,0,0,0}, acc2 = {0,0,0,0}, acc3 = {0,0,0,0};

    const float*  xrow = x + (size_t)(m0 + cl) * 1024;
    const ushort* wbase = Wt + (size_t)(n0 + cl) * 1024;

    for (int ks = 0; ks < 32; ++ks) {
        const int k = ks * 32 + g4 * 8;
        f4 xa = *(const f4*)&xrow[k];
        f4 xb2 = *(const f4*)&xrow[k + 4];
        v8cast bf;
        ((uint*)&bf.u)[0] = (rnd16(xa.y) << 16) | rnd16(xa.x);
        ((uint*)&bf.u)[1] = (rnd16(xa.w) << 16) | rnd16(xa.z);
        ((uint*)&bf.u)[2] = (rnd16(xb2.y) << 16) | rnd16(xb2.x);
        ((uint*)&bf.u)[3] = (rnd16(xb2.w) << 16) | rnd16(xb2.z);
        s8v a0 = *(const s8v*)(wbase + 0 * 16 * 1024 + k);
        s8v a1 = *(const s8v*)(wbase + 1 * 16 * 1024 + k);
        s8v a2 = *(const s8v*)(wbase + 2 * 16 * 1024 + k);
        s8v a3 = *(const s8v*)(wbase + 3 * 16 * 1024 + k);
        acc0 = __builtin_amdgcn_mfma_f32_16x16x32_bf16(a0, bf.s, acc0, 0, 0, 0);
        acc1 = __builtin_amdgcn_mfma_f32_16x16x32_bf16(a1, bf.s, acc1, 0, 0, 0);
        acc2 = __builtin_amdgcn_mfma_f32_16x16x32_bf16(a2, bf.s, acc2, 0, 0, 0);
        acc3 = __builtin_amdgcn_mfma_f32_16x16x32_bf16(a3, bf.s, acc3, 0, 0, 0);
    }

    const int m = m0 + cl;
    const int nbase = n0 + g4 * 4;
    ushort* obase = (n0 < 256) ? (sqb + (size_t)m * 256 + nbase)
                               : (skb + (size_t)m * 256 + (nbase - 256));
    f4 accs[4] = {acc0, acc1, acc2, acc3};
    #pragma unroll
    for (int t = 0; t < 4; ++t) {
        u2 pk;
        pk.x = (rnd16(accs[t][1]) << 16) | rnd16(accs[t][0]);
        pk.y = (rnd16(accs[t][3]) << 16) | rnd16(accs[t][2]);
        *(u2*)(obase + t * 16) = pk;
    }
}

// ---------------------------------------------------------------------------
// Kernel 2: MFMA scores + mask + gumbel + softmax (swapped operands).
// EXACT R10 structure (best measured: 162us, VGPR 84, no spill) with the
// zero-fill removed (now in the dedicated zfill kernel). mfma(A=sk,B=sq):
// C col=lane&15 -> output row i, C rows -> 4 consecutive cols j; wave does
// two adjacent tiles per iteration (full 128B-line coverage); exp packed
// 2xbf16 in p[8][2]; pass 2 = unpack+scale+store.
// ---------------------------------------------------------------------------
__global__ __launch_bounds__(512) void score_mfma(
    const ushort* __restrict__ sqb,     // [4096][256] bf16 bits
    const ushort* __restrict__ skb,     // [4096][256] bf16 bits
    const float*  __restrict__ gumbel,  // [B,H,T,T] f32
    const int*    __restrict__ mask,    // [H,T,T] int32 bool
    float* __restrict__ out)            // [B,H,T,T] f32
{
    const int tid = threadIdx.x;
    const int l   = tid & 63;
    const int w   = __builtin_amdgcn_readfirstlane(tid) >> 6;  // wave id 0..7
    const int bh  = blockIdx.x & 15;
    const int sp  = blockIdx.x >> 4;     // 0..63
    const int h   = bh & (HH - 1);
    const int b   = bh >> 3;
    const int cl  = l & 15;              // C col -> output row i offset
    const int g4  = l >> 4;              // 0..3  -> j sub-block
    const float RS = 0.17677669529663687f;  // 1/sqrt(RD)

    __shared__ float sums_lds[8][16];

    const ushort* sqbase = sqb + ((size_t)b * TT) * 256 + h * RDIM + g4 * 8;
    const ushort* skbase = skb + ((size_t)b * TT) * 256 + h * RDIM + g4 * 8;
    const float*  gb = gumbel + (size_t)bh * TT * TT;
    const int*    mb = mask + (size_t)h * TT * TT;
    float*        ob = out + (size_t)bh * TT * TT;

    #pragma unroll 1
    for (int half = 0; half < 2; ++half) {
        const int s      = half ? (127 - sp) : sp;
        const int i0     = s * 16;
        const int ntiles = s + 1;        // live 16-col tiles (max 128)
        const int i      = i0 + cl;      // this lane's output row

        // B fragment (sq row i): strip-invariant
        s8v bfrag = *(const s8v*)(sqbase + (size_t)i * 256);

        const float* grow = gb + (size_t)i * TT;
        const int*   mrow = mb + (size_t)i * TT;
        float*       orow = ob + (size_t)i * TT;

        // ---- pass 1: MFMA + exp, pack bf16, accumulate row sum ----
        float sum = 0.f;
        u2 p[8][2];
        #pragma unroll
        for (int it = 0; it < 8; ++it) {
            const int jt0 = 2 * w + it * 16;   // wave-uniform pair base
            #pragma unroll
            for (int u = 0; u < 2; ++u) {
                const int jt = jt0 + u;
                if (jt < ntiles) {
                    // A fragment (sk row j): row = jt*16 + (lane&15)
                    s8v afrag = *(const s8v*)(skbase + (size_t)(jt * 16 + cl) * 256);
                    f4 z = {0.f, 0.f, 0.f, 0.f};
                    f4 c = __builtin_amdgcn_mfma_f32_16x16x32_bf16(
                               afrag, bfrag, z, 0, 0, 0);
                    const int jb = jt * 16 + g4 * 4;   // 4 consecutive cols
                    f4 gv = *(const f4*)&grow[jb];
                    i4 mv = *(const i4*)&mrow[jb];
                    float e0 = (jb + 0 > i || mv.x) ? 0.f : __expf(fmaf(c[0], RS, gv.x));
                    float e1 = (jb + 1 > i || mv.y) ? 0.f : __expf(fmaf(c[1], RS, gv.y));
                    float e2 = (jb + 2 > i || mv.z) ? 0.f : __expf(fmaf(c[2], RS, gv.z));
                    float e3 = (jb + 3 > i || mv.w) ? 0.f : __expf(fmaf(c[3], RS, gv.w));
                    sum += (e0 + e1) + (e2 + e3);
                    p[it][u].x = (rnd16(e1) << 16) | rnd16(e0);
                    p[it][u].y = (rnd16(e3) << 16) | rnd16(e2);
                }
            }
        }

        // ---- row-sum reduce: across g4 groups, then across waves ----
        sum += __shfl_xor(sum, 16);
        sum += __shfl_xor(sum, 32);
        if (l < 16) sums_lds[w][l] = sum;
        __syncthreads();
        float t = 0.f;
        #pragma unroll
        for (int ww = 0; ww < 8; ++ww) t += sums_lds[ww][cl];
        const float rinv = 1.0f / t;     // diagonal always live -> t > 0
        __syncthreads();                 // LDS reused by next half

        // ---- pass 2: unpack + scale + store (plain cached stores) ----
        #pragma unroll
        for (int it = 0; it < 8; ++it) {
            const int jt0 = 2 * w + it * 16;
            #pragma unroll
            for (int u = 0; u < 2; ++u) {
                const int jt = jt0 + u;
                if (jt < ntiles) {
                    const int jb = jt * 16 + g4 * 4;
                    f4 v;
                    v.x = __uint_as_float(p[it][u].x << 16) * rinv;
                    v.y = __uint_as_float(p[it][u].x & 0xffff0000u) * rinv;
                    v.z = __uint_as_float(p[it][u].y << 16) * rinv;
                    v.w = __uint_as_float(p[it][u].y & 0xffff0000u) * rinv;
                    *(f4*)&orow[jb] = v;
                }
            }
        }
    }
}

extern "C" void kernel_launch(void* const* d_in, const int* in_sizes, int n_in,
                              void* d_out, int out_size, void* d_ws, size_t ws_size,
                              hipStream_t stream) {
    const float* x      = (const float*)d_in[0];
    const int*   bmask  = (const int*)d_in[1];   // bool -> int32 per harness
    const float* gumbel = (const float*)d_in[2];
    const float* Wq     = (const float*)d_in[3];
    const float* Wk     = (const float*)d_in[4];
    float* out = (float*)d_out;

    ushort* sqb = (ushort*)d_ws;                       // 4096*256 bf16 = 2 MB
    ushort* skb = sqb + (size_t)4096 * 256;            // 2 MB
    ushort* Wt  = skb + (size_t)4096 * 256;            // 512*1024 bf16 = 1 MB

    // dead-region memset first (no dependencies; memset-class BW)
    zfill<<<1024, 512, 0, stream>>>(out);

    wt_prep<<<dim3(16, 8), 256, 0, stream>>>(Wq, Wk, Wt);
    proj_mfma<<<dim3(64, 8), 256, 0, stream>>>(x, Wt, sqb, skb);

    // 16 bh x 64 balanced strip-pairs, 512 thr (8 waves) each
    score_mfma<<<1024, 512, 0, stream>>>(sqb, skb, gumbel, bmask, out);
}

// Round 19
// 183.418 us; speedup vs baseline: 1.0771x; 1.0385x over previous
//
#include <hip/hip_runtime.h>
#include <hip/hip_bf16.h>
#include <math.h>

// Problem constants
#define TT    2048
#define HH    8
#define RDIM  32
#define BB    2

typedef float  f4  __attribute__((ext_vector_type(4)));
typedef int    i4  __attribute__((ext_vector_type(4)));
typedef uint   u2  __attribute__((ext_vector_type(2)));
typedef uint   u4  __attribute__((ext_vector_type(4)));
typedef short  s8v __attribute__((ext_vector_type(8)));   // 8 x bf16 bits (4 VGPR)

// round-to-nearest f32 -> bf16 bits
__device__ __forceinline__ uint rnd16(float x) {
    return (__float_as_uint(x) + 0x8000u) >> 16;
}

union v8cast { u4 u; s8v s; };

// ---------------------------------------------------------------------------
// Kernel 0: Wt prep — transpose (Wq|Wk)[1024][256+256] f32 -> Wt[512][1024]
// bf16 (Wt[n][k] = W[k][n]). LDS-tiled 64x64. 1 MB output, L2-resident.
// ---------------------------------------------------------------------------
__global__ __launch_bounds__(256) void wt_prep(
    const float* __restrict__ Wq,
    const float* __restrict__ Wk,
    ushort* __restrict__ Wt)
{
    __shared__ float T[64][68];
    const int k0 = blockIdx.x * 64;
    const int n0 = blockIdx.y * 64;
    const float* W = (n0 < 256) ? Wq : Wk;
    const int nloc = n0 & 255;
    const int tid = threadIdx.x;

    #pragma unroll
    for (int r = 0; r < 4; ++r) {
        int kl  = (tid >> 4) + r * 16;
        int nl4 = (tid & 15) * 4;
        f4 v = *(const f4*)&W[(size_t)(k0 + kl) * 256 + nloc + nl4];
        T[nl4 + 0][kl] = v.x;
        T[nl4 + 1][kl] = v.y;
        T[nl4 + 2][kl] = v.z;
        T[nl4 + 3][kl] = v.w;
    }
    __syncthreads();

    const int nl = tid >> 2;
    const int kq = (tid & 3) * 16;
    u4 o0, o1;
    #pragma unroll
    for (int j = 0; j < 4; ++j) {
        uint lo = rnd16(T[nl][kq + 2 * j]);
        uint hi = rnd16(T[nl][kq + 2 * j + 1]);
        ((uint*)&o0)[j] = (hi << 16) | lo;
    }
    #pragma unroll
    for (int j = 0; j < 4; ++j) {
        uint lo = rnd16(T[nl][kq + 8 + 2 * j]);
        uint hi = rnd16(T[nl][kq + 8 + 2 * j + 1]);
        ((uint*)&o1)[j] = (hi << 16) | lo;
    }
    ushort* dst = Wt + (size_t)(n0 + nl) * 1024 + k0 + kq;
    *(u4*)dst = o0;
    *(u4*)(dst + 8) = o1;
}

// ---------------------------------------------------------------------------
// Kernel 1: MFMA projection + FUSED dead-region zero-fill.
// proj: sq/sk[m][n] = sum_k x[m][k] * Wt[n][k]; mfma(A=Wt,B=x), lane owns
// col m, 4 consecutive n. proj is latency-bound (~26us, ~20MB traffic);
// the 134MB causally-dead output fill rides along with PLAIN cached
// full-line stores (R18 evidence: fillBuffer hits 6.4-7 TB/s plain; NT
// stores measured ~2x slower). 512 blocks x balanced 4-strip slice.
// ---------------------------------------------------------------------------
__global__ __launch_bounds__(256) void proj_mfma(
    const float* __restrict__ x,       // [4096][1024] f32
    const ushort* __restrict__ Wt,     // [512][1024] bf16 bits
    ushort* __restrict__ sqb,          // [4096][256] bf16 bits
    ushort* __restrict__ skb,          // [4096][256] bf16 bits
    float* __restrict__ out)           // [B,H,T,T] f32 (dead region only)
{
    const int tid = threadIdx.x;
    const int l   = tid & 63;
    const int w   = __builtin_amdgcn_readfirstlane(tid) >> 6;  // 0..3
    const int cl  = l & 15;
    const int g4  = l >> 4;
    const int m0  = (blockIdx.x * 4 + w) * 16;   // m-tile
    const int n0  = blockIdx.y * 64;             // n-block (64 wide)

    f4 acc0 = {0,0,0,0}, acc1 = {0,0,0,0}, acc2 = {0,0,0,0}, acc3 = {0,0,0,0};

    const float*  xrow = x + (size_t)(m0 + cl) * 1024;
    const ushort* wbase = Wt + (size_t)(n0 + cl) * 1024;

    for (int ks = 0; ks < 32; ++ks) {
        const int k = ks * 32 + g4 * 8;
        f4 xa = *(const f4*)&xrow[k];
        f4 xb2 = *(const f4*)&xrow[k + 4];
        v8cast bf;
        ((uint*)&bf.u)[0] = (rnd16(xa.y) << 16) | rnd16(xa.x);
        ((uint*)&bf.u)[1] = (rnd16(xa.w) << 16) | rnd16(xa.z);
        ((uint*)&bf.u)[2] = (rnd16(xb2.y) << 16) | rnd16(xb2.x);
        ((uint*)&bf.u)[3] = (rnd16(xb2.w) << 16) | rnd16(xb2.z);
        s8v a0 = *(const s8v*)(wbase + 0 * 16 * 1024 + k);
        s8v a1 = *(const s8v*)(wbase + 1 * 16 * 1024 + k);
        s8v a2 = *(const s8v*)(wbase + 2 * 16 * 1024 + k);
        s8v a3 = *(const s8v*)(wbase + 3 * 16 * 1024 + k);
        acc0 = __builtin_amdgcn_mfma_f32_16x16x32_bf16(a0, bf.s, acc0, 0, 0, 0);
        acc1 = __builtin_amdgcn_mfma_f32_16x16x32_bf16(a1, bf.s, acc1, 0, 0, 0);
        acc2 = __builtin_amdgcn_mfma_f32_16x16x32_bf16(a2, bf.s, acc2, 0, 0, 0);
        acc3 = __builtin_amdgcn_mfma_f32_16x16x32_bf16(a3, bf.s, acc3, 0, 0, 0);
    }

    const int m = m0 + cl;
    const int nbase = n0 + g4 * 4;
    ushort* obase = (n0 < 256) ? (sqb + (size_t)m * 256 + nbase)
                               : (skb + (size_t)m * 256 + (nbase - 256));
    f4 accs[4] = {acc0, acc1, acc2, acc3};
    #pragma unroll
    for (int t = 0; t < 4; ++t) {
        u2 pk;
        pk.x = (rnd16(accs[t][1]) << 16) | rnd16(accs[t][0]);
        pk.y = (rnd16(accs[t][3]) << 16) | rnd16(accs[t][2]);
        *(u2*)(obase + t * 16) = pk;
    }

    // ---- fused zero-fill: balanced 4-strip slice per block ----
    // zb in 0..511; strips {sp2, 63-sp2, 64+sp2, 127-sp2} of bh = zb&15:
    // total dead cols per slice = 254 tile-widths (uniform across blocks).
    {
        const int zb  = blockIdx.y * 64 + blockIdx.x;
        const int zbh = zb & 15;
        const int sp2 = zb >> 4;             // 0..31
        float* ob = out + (size_t)zbh * TT * TT;
        const int ss[4] = {sp2, 63 - sp2, 64 + sp2, 127 - sp2};
        #pragma unroll
        for (int q = 0; q < 4; ++q) {
            const int s  = ss[q];
            const int i0 = s * 16;
            const int zs = (s + 1) * 16;     // first dead col
            for (int r = 0; r < 16; ++r) {
                float* row = &ob[(size_t)(i0 + r) * TT];
                for (int cz = zs + tid * 4; cz < TT; cz += 256 * 4) {
                    f4 zz = {0.f, 0.f, 0.f, 0.f};
                    *(f4*)&row[cz] = zz;     // plain cached full-line stores
                }
            }
        }
    }
}

// ---------------------------------------------------------------------------
// Kernel 2: MFMA scores + mask + gumbel + softmax (swapped operands).
// R10 structure (best measured), zero-fill removed, and the SECOND barrier
// per half removed via double-buffered sums_lds: pass-2 stores of half 0
// can overlap pass-1 loads of half 1 across waves.
// ---------------------------------------------------------------------------
__global__ __launch_bounds__(512) void score_mfma(
    const ushort* __restrict__ sqb,     // [4096][256] bf16 bits
    const ushort* __restrict__ skb,     // [4096][256] bf16 bits
    const float*  __restrict__ gumbel,  // [B,H,T,T] f32
    const int*    __restrict__ mask,    // [H,T,T] int32 bool
    float* __restrict__ out)            // [B,H,T,T] f32
{
    const int tid = threadIdx.x;
    const int l   = tid & 63;
    const int w   = __builtin_amdgcn_readfirstlane(tid) >> 6;  // wave id 0..7
    const int bh  = blockIdx.x & 15;
    const int sp  = blockIdx.x >> 4;     // 0..63
    const int h   = bh & (HH - 1);
    const int b   = bh >> 3;
    const int cl  = l & 15;              // C col -> output row i offset
    const int g4  = l >> 4;              // 0..3  -> j sub-block
    const float RS = 0.17677669529663687f;  // 1/sqrt(RD)

    __shared__ float sums_lds[2][8][16]; // double-buffered: one barrier/half

    const ushort* sqbase = sqb + ((size_t)b * TT) * 256 + h * RDIM + g4 * 8;
    const ushort* skbase = skb + ((size_t)b * TT) * 256 + h * RDIM + g4 * 8;
    const float*  gb = gumbel + (size_t)bh * TT * TT;
    const int*    mb = mask + (size_t)h * TT * TT;
    float*        ob = out + (size_t)bh * TT * TT;

    #pragma unroll 1
    for (int half = 0; half < 2; ++half) {
        const int s      = half ? (127 - sp) : sp;
        const int i0     = s * 16;
        const int ntiles = s + 1;        // live 16-col tiles (max 128)
        const int i      = i0 + cl;      // this lane's output row

        // B fragment (sq row i): strip-invariant
        s8v bfrag = *(const s8v*)(sqbase + (size_t)i * 256);

        const float* grow = gb + (size_t)i * TT;
        const int*   mrow = mb + (size_t)i * TT;
        float*       orow = ob + (size_t)i * TT;

        // ---- pass 1: MFMA + exp, pack bf16, accumulate row sum ----
        float sum = 0.f;
        u2 p[8][2];
        #pragma unroll
        for (int it = 0; it < 8; ++it) {
            const int jt0 = 2 * w + it * 16;   // wave-uniform pair base
            #pragma unroll
            for (int u = 0; u < 2; ++u) {
                const int jt = jt0 + u;
                if (jt < ntiles) {
                    // A fragment (sk row j): row = jt*16 + (lane&15)
                    s8v afrag = *(const s8v*)(skbase + (size_t)(jt * 16 + cl) * 256);
                    f4 z = {0.f, 0.f, 0.f, 0.f};
                    f4 c = __builtin_amdgcn_mfma_f32_16x16x32_bf16(
                               afrag, bfrag, z, 0, 0, 0);
                    const int jb = jt * 16 + g4 * 4;   // 4 consecutive cols
                    f4 gv = *(const f4*)&grow[jb];
                    i4 mv = *(const i4*)&mrow[jb];
                    float e0 = (jb + 0 > i || mv.x) ? 0.f : __expf(fmaf(c[0], RS, gv.x));
                    float e1 = (jb + 1 > i || mv.y) ? 0.f : __expf(fmaf(c[1], RS, gv.y));
                    float e2 = (jb + 2 > i || mv.z) ? 0.f : __expf(fmaf(c[2], RS, gv.z));
                    float e3 = (jb + 3 > i || mv.w) ? 0.f : __expf(fmaf(c[3], RS, gv.w));
                    sum += (e0 + e1) + (e2 + e3);
                    p[it][u].x = (rnd16(e1) << 16) | rnd16(e0);
                    p[it][u].y = (rnd16(e3) << 16) | rnd16(e2);
                }
            }
        }

        // ---- row-sum reduce: across g4 groups, then across waves ----
        sum += __shfl_xor(sum, 16);
        sum += __shfl_xor(sum, 32);
        if (l < 16) sums_lds[half][w][l] = sum;
        __syncthreads();                 // single barrier per half
        float t = 0.f;
        #pragma unroll
        for (int ww = 0; ww < 8; ++ww) t += sums_lds[half][ww][cl];
        const float rinv = 1.0f / t;     // diagonal always live -> t > 0

        // ---- pass 2: unpack + scale + store (plain cached stores) ----
        #pragma unroll
        for (int it = 0; it < 8; ++it) {
            const int jt0 = 2 * w + it * 16;
            #pragma unroll
            for (int u = 0; u < 2; ++u) {
                const int jt = jt0 + u;
                if (jt < ntiles) {
                    const int jb = jt * 16 + g4 * 4;
                    f4 v;
                    v.x = __uint_as_float(p[it][u].x << 16) * rinv;
                    v.y = __uint_as_float(p[it][u].x & 0xffff0000u) * rinv;
                    v.z = __uint_as_float(p[it][u].y << 16) * rinv;
                    v.w = __uint_as_float(p[it][u].y & 0xffff0000u) * rinv;
                    *(f4*)&orow[jb] = v;
                }
            }
        }
    }
}

extern "C" void kernel_launch(void* const* d_in, const int* in_sizes, int n_in,
                              void* d_out, int out_size, void* d_ws, size_t ws_size,
                              hipStream_t stream) {
    const float* x      = (const float*)d_in[0];
    const int*   bmask  = (const int*)d_in[1];   // bool -> int32 per harness
    const float* gumbel = (const float*)d_in[2];
    const float* Wq     = (const float*)d_in[3];
    const float* Wk     = (const float*)d_in[4];
    float* out = (float*)d_out;

    ushort* sqb = (ushort*)d_ws;                       // 4096*256 bf16 = 2 MB
    ushort* skb = sqb + (size_t)4096 * 256;            // 2 MB
    ushort* Wt  = skb + (size_t)4096 * 256;            // 512*1024 bf16 = 1 MB

    wt_prep<<<dim3(16, 8), 256, 0, stream>>>(Wq, Wk, Wt);

    // projection + fused dead-region zero-fill (plain cached stores)
    proj_mfma<<<dim3(64, 8), 256, 0, stream>>>(x, Wt, sqb, skb, out);

    // 16 bh x 64 balanced strip-pairs, 512 thr (8 waves) each
    score_mfma<<<1024, 512, 0, stream>>>(sqb, skb, gumbel, bmask, out);
}